// Round 2
// baseline (271.934 us; speedup 1.0000x reference)
//
#include <hip/hip_runtime.h>
#include <hip/hip_bf16.h>

#define B_SZ 4096
#define DZ   512
#define H_SZ 2048
#define DY   10

typedef __attribute__((ext_vector_type(8))) __bf16 bf16x8;
typedef __attribute__((ext_vector_type(4))) float  f32x4;
typedef __attribute__((ext_vector_type(8))) unsigned short us8;

__device__ inline unsigned short f2bf(float f) {
    unsigned u = __float_as_uint(f);
    u += 0x7fffu + ((u >> 16) & 1u);   // round-to-nearest-even
    return (unsigned short)(u >> 16);
}
__device__ inline float bf2f(unsigned short s) {
    return __uint_as_float(((unsigned)s) << 16);
}

// ---------------------------------------------------------------------------
// 32x32-tile fp32 GEMM helper: C = A[m0:+32, 0:klen] * B[0:klen, n0:+32]
// A,B row-major, row stride 512. 256 threads, 2x2 per thread.
// ---------------------------------------------------------------------------
__device__ inline void gemm32_tile(const float* __restrict__ Ab,
                                   const float* __restrict__ Bb,
                                   int m0, int n0, int klen, int t,
                                   float* sA, float* sB, float acc[2][2]) {
    const int tx = t & 15, ty = t >> 4;
    acc[0][0] = acc[0][1] = acc[1][0] = acc[1][1] = 0.f;
    for (int kk = 0; kk < klen; kk += 16) {
        { // stage A transposed: sA[k][m], 32x16 tile
            int rr = t >> 3, cc = (t & 7) * 2;
            float2 v = *(const float2*)&Ab[(size_t)(m0 + rr) * 512 + kk + cc];
            sA[cc * 36 + rr]       = v.x;
            sA[(cc + 1) * 36 + rr] = v.y;
        }
        { // stage B natural: sB[k][n], 16x32 tile
            int kr = t >> 4, nn = (t & 15) * 2;
            *(float2*)&sB[kr * 36 + nn] =
                *(const float2*)&Bb[(size_t)(kk + kr) * 512 + n0 + nn];
        }
        __syncthreads();
#pragma unroll
        for (int k = 0; k < 16; ++k) {
            float2 a = *(const float2*)&sA[k * 36 + ty * 2];
            float2 b = *(const float2*)&sB[k * 36 + tx * 2];
            acc[0][0] += a.x * b.x; acc[0][1] += a.x * b.y;
            acc[1][0] += a.y * b.x; acc[1][1] += a.y * b.y;
        }
        __syncthreads();
    }
}

// ---------------------------------------------------------------------------
// k_init (grid 1024 x 256): M0 = I + dt*A ; x -> bf16 ; y = b2 broadcast
// ---------------------------------------------------------------------------
__global__ __launch_bounds__(256) void k_init(
    const float* __restrict__ Ain, const float* __restrict__ x,
    const float* __restrict__ b2, float* __restrict__ M0,
    unsigned short* __restrict__ x_bf, float* __restrict__ y) {
    const int gid = blockIdx.x * 256 + threadIdx.x;   // 0 .. 262143
    const float dt = 1.0f / 64.0f;

    int r = gid >> 9, c = gid & 511;
    M0[gid] = dt * Ain[gid] + (r == c ? 1.0f : 0.0f);

    const float4* x4 = (const float4*)x;
    float4 v0 = x4[gid * 2], v1 = x4[gid * 2 + 1];
    us8 o;
    o[0] = f2bf(v0.x); o[1] = f2bf(v0.y); o[2] = f2bf(v0.z); o[3] = f2bf(v0.w);
    o[4] = f2bf(v1.x); o[5] = f2bf(v1.y); o[6] = f2bf(v1.z); o[7] = f2bf(v1.w);
    *(us8*)&x_bf[gid * 8] = o;

    if (gid < B_SZ * DY) y[gid] = b2[gid % DY];
}

// ---------------------------------------------------------------------------
// k_sq (grid 256 x 256): dst = src * src   (512x512 fp32, 32x32 tiles)
// ---------------------------------------------------------------------------
__global__ __launch_bounds__(256) void k_sq(const float* __restrict__ src,
                                            float* __restrict__ dst) {
    __shared__ float sA[16 * 36];
    __shared__ float sB[16 * 36];
    const int t = threadIdx.x, bid = blockIdx.x;
    const int m0 = (bid >> 4) * 32, n0 = (bid & 15) * 32;
    const int tx = t & 15, ty = t >> 4;
    float acc[2][2];
    gemm32_tile(src, src, m0, n0, 512, t, sA, sB, acc);
    *(float2*)&dst[(size_t)(m0 + ty * 2) * DZ + n0 + tx * 2] =
        make_float2(acc[0][0], acc[0][1]);
    *(float2*)&dst[(size_t)(m0 + ty * 2 + 1) * DZ + n0 + tx * 2] =
        make_float2(acc[1][0], acc[1][1]);
}

// ---------------------------------------------------------------------------
// k_fold (grid 1024 x 256): w1f = bf16(W1 @ M)   (2048x512)
// ---------------------------------------------------------------------------
__global__ __launch_bounds__(256) void k_fold(const float* __restrict__ W1,
                                              const float* __restrict__ M,
                                              unsigned short* __restrict__ w1f) {
    __shared__ float sA[16 * 36];
    __shared__ float sB[16 * 36];
    const int t = threadIdx.x, bid = blockIdx.x;
    const int m0 = (bid >> 4) * 32, n0 = (bid & 15) * 32;
    const int tx = t & 15, ty = t >> 4;
    float acc[2][2];
    gemm32_tile(W1, M, m0, n0, 512, t, sA, sB, acc);
    *(ushort2*)&w1f[(size_t)(m0 + ty * 2) * DZ + n0 + tx * 2] =
        make_ushort2(f2bf(acc[0][0]), f2bf(acc[0][1]));
    *(ushort2*)&w1f[(size_t)(m0 + ty * 2 + 1) * DZ + n0 + tx * 2] =
        make_ushort2(f2bf(acc[1][0]), f2bf(acc[1][1]));
}

// ---------------------------------------------------------------------------
// Main GEMM: h = relu(x_bf @ W1f^T + b1) fused with y += h @ W2^T (atomicAdd).
// 128x128 tile, BK=64, 4 waves each 64x64 via 4x4 MFMA 16x16x32 bf16.
// Plain vectorized staging with XOR-swizzled 16B chunks (conflict-free reads).
// ---------------------------------------------------------------------------
union SmemU {
    struct { unsigned short A[128 * 64]; unsigned short B[128 * 64]; } s; // 32 KB
    struct { unsigned short h[128 * 130]; float w2[DY * 132]; } e;        // 38.6 KB
};

__global__ __launch_bounds__(256, 2) void mlp_kernel(
    const unsigned short* __restrict__ x_bf,
    const unsigned short* __restrict__ w1f,
    const float* __restrict__ b1, const float* __restrict__ W2,
    float* __restrict__ y) {
    __shared__ SmemU sm;
    const int t    = threadIdx.x;
    const int lane = t & 63, w = t >> 6;
    const int quad = lane >> 4, l16 = lane & 15;
    const int wm = (w & 1) * 64, wn = (w >> 1) * 64;
    const int m0g = blockIdx.x * 128, n0g = blockIdx.y * 128;

    f32x4 acc[4][4];
#pragma unroll
    for (int i = 0; i < 4; ++i)
#pragma unroll
        for (int j = 0; j < 4; ++j) acc[i][j] = (f32x4){0.f, 0.f, 0.f, 0.f};

    for (int kt = 0; kt < 8; ++kt) {
#pragma unroll
        for (int c = 0; c < 4; ++c) {
            int idx = c * 256 + t;            // 16B-chunk id, 0..1023
            int row = idx >> 3, cc = idx & 7; // 8 chunks (64 bf16) per row
            int ccs = cc ^ (row & 7);         // XOR swizzle
            us8 va = *(const us8*)&x_bf[(size_t)(m0g + row) * 512 + kt * 64 + cc * 8];
            *(us8*)&sm.s.A[row * 64 + ccs * 8] = va;
            us8 vb = *(const us8*)&w1f[(size_t)(n0g + row) * 512 + kt * 64 + cc * 8];
            *(us8*)&sm.s.B[row * 64 + ccs * 8] = vb;
        }
        __syncthreads();
#pragma unroll
        for (int ks = 0; ks < 2; ++ks) {
            bf16x8 af[4], bfr[4];
#pragma unroll
            for (int i = 0; i < 4; ++i) {
                int ra = wm + i * 16 + l16;
                int rb = wn + i * 16 + l16;
                int ca = (ks * 4 + quad) ^ (ra & 7);
                int cb = (ks * 4 + quad) ^ (rb & 7);
                af[i]  = *(const bf16x8*)&sm.s.A[ra * 64 + ca * 8];
                bfr[i] = *(const bf16x8*)&sm.s.B[rb * 64 + cb * 8];
            }
#pragma unroll
            for (int i = 0; i < 4; ++i)
#pragma unroll
                for (int j = 0; j < 4; ++j)
                    acc[i][j] = __builtin_amdgcn_mfma_f32_16x16x32_bf16(
                        af[i], bfr[j], acc[i][j], 0, 0, 0);
        }
        __syncthreads();
    }

    // ---- epilogue: bias + relu -> LDS (n-major), then y += h @ W2^T ----
    float bias[4];
#pragma unroll
    for (int j = 0; j < 4; ++j) bias[j] = b1[n0g + wn + j * 16 + l16];
#pragma unroll
    for (int i = 0; i < 4; ++i)
#pragma unroll
        for (int j = 0; j < 4; ++j)
#pragma unroll
            for (int r = 0; r < 4; ++r) {
                float h = acc[i][j][r] + bias[j];
                h = h > 0.f ? h : 0.f;
                sm.e.h[(wn + j * 16 + l16) * 130 + (wm + i * 16 + quad * 4 + r)] = f2bf(h);
            }
    for (int i = t; i < DY * 128; i += 256) {
        int d = i >> 7, n = i & 127;
        sm.e.w2[d * 132 + n] = W2[(size_t)d * H_SZ + n0g + n];
    }
    __syncthreads();
    {
        int m = t >> 1, dg = t & 1;
        float s0 = 0.f, s1 = 0.f, s2 = 0.f, s3 = 0.f, s4 = 0.f;
        const float* wrow = &sm.e.w2[dg * 5 * 132];
#pragma unroll 4
        for (int n = 0; n < 128; ++n) {
            float h = bf2f(sm.e.h[n * 130 + m]);
            s0 += h * wrow[n];
            s1 += h * wrow[132 + n];
            s2 += h * wrow[264 + n];
            s3 += h * wrow[396 + n];
            s4 += h * wrow[528 + n];
        }
        float* yp = &y[(size_t)(m0g + m) * DY + dg * 5];
        atomicAdd(yp + 0, s0);
        atomicAdd(yp + 1, s1);
        atomicAdd(yp + 2, s2);
        atomicAdd(yp + 3, s3);
        atomicAdd(yp + 4, s4);
    }
}

// ---------------------------------------------------------------------------
extern "C" void kernel_launch(void* const* d_in, const int* in_sizes, int n_in,
                              void* d_out, int out_size, void* d_ws, size_t ws_size,
                              hipStream_t stream) {
    const float* x  = (const float*)d_in[0];
    const float* A  = (const float*)d_in[1];
    const float* W1 = (const float*)d_in[2];
    const float* b1 = (const float*)d_in[3];
    const float* W2 = (const float*)d_in[4];
    const float* b2 = (const float*)d_in[5];
    float* y = (float*)d_out;

    char* ws = (char*)d_ws;
    float* M0 = (float*)ws;                                  // 1 MB
    float* M1 = (float*)(ws + (1u << 20));                   // 1 MB
    unsigned short* x_bf = (unsigned short*)(ws + 2u * (1u << 20)); // 4 MB
    unsigned short* w1f  = (unsigned short*)(ws + 6u * (1u << 20)); // 2 MB

    k_init<<<1024, 256, 0, stream>>>(A, x, b2, M0, x_bf, y);
    // 6 squarings: (I+dtA)^64, ping-pong M0 <-> M1, result lands in M0
    k_sq<<<256, 256, 0, stream>>>(M0, M1);
    k_sq<<<256, 256, 0, stream>>>(M1, M0);
    k_sq<<<256, 256, 0, stream>>>(M0, M1);
    k_sq<<<256, 256, 0, stream>>>(M1, M0);
    k_sq<<<256, 256, 0, stream>>>(M0, M1);
    k_sq<<<256, 256, 0, stream>>>(M1, M0);
    k_fold<<<1024, 256, 0, stream>>>(W1, M0, w1f);
    mlp_kernel<<<dim3(32, 16), dim3(256), 0, stream>>>(x_bf, w1f, b1, W2, y);
}

// Round 3
// 192.674 us; speedup vs baseline: 1.4114x; 1.4114x over previous
//
#include <hip/hip_runtime.h>
#include <hip/hip_bf16.h>

#define B_SZ 4096
#define DZ   512
#define H_SZ 2048
#define DY   10

typedef __attribute__((ext_vector_type(8))) __bf16 bf16x8;
typedef __attribute__((ext_vector_type(4))) float  f32x4;
typedef __attribute__((ext_vector_type(8))) unsigned short us8;

__device__ inline unsigned short f2bf(float f) {
    unsigned u = __float_as_uint(f);
    u += 0x7fffu + ((u >> 16) & 1u);   // round-to-nearest-even
    return (unsigned short)(u >> 16);
}
__device__ inline float bf2f(unsigned short s) {
    return __uint_as_float(((unsigned)s) << 16);
}

// ===========================================================================
// k_init (grid 256 x 256):
//   x -> bf16 ; W1 -> bf16 ; y = b2 broadcast ;
//   blocks 0..63: E0 = dt*A (fp32) + bf16 copy hi + transposed bf16 copy hiT
// ===========================================================================
__global__ __launch_bounds__(256) void k_init(
    const float* __restrict__ Ain, const float* __restrict__ x,
    const float* __restrict__ W1, const float* __restrict__ b2,
    float* __restrict__ E, unsigned short* __restrict__ hi,
    unsigned short* __restrict__ hiT, unsigned short* __restrict__ x_bf,
    unsigned short* __restrict__ w1_bf, float* __restrict__ y) {
    __shared__ float epi[64 * 68];
    const int b = blockIdx.x, t = threadIdx.x;
    const float dt = 1.0f / 64.0f;

    // ---- x -> bf16 (4096x512 = 262144 us8 chunks) ----
    const float4* x4 = (const float4*)x;
#pragma unroll
    for (int i = 0; i < 4; ++i) {
        int id = b * 1024 + i * 256 + t;
        float4 v0 = x4[(size_t)id * 2], v1 = x4[(size_t)id * 2 + 1];
        us8 o;
        o[0] = f2bf(v0.x); o[1] = f2bf(v0.y); o[2] = f2bf(v0.z); o[3] = f2bf(v0.w);
        o[4] = f2bf(v1.x); o[5] = f2bf(v1.y); o[6] = f2bf(v1.z); o[7] = f2bf(v1.w);
        *(us8*)&x_bf[(size_t)id * 8] = o;
    }
    // ---- W1 -> bf16 (2048x512 = 131072 us8 chunks) ----
    const float4* w4 = (const float4*)W1;
#pragma unroll
    for (int i = 0; i < 2; ++i) {
        int id = b * 512 + i * 256 + t;
        float4 v0 = w4[(size_t)id * 2], v1 = w4[(size_t)id * 2 + 1];
        us8 o;
        o[0] = f2bf(v0.x); o[1] = f2bf(v0.y); o[2] = f2bf(v0.z); o[3] = f2bf(v0.w);
        o[4] = f2bf(v1.x); o[5] = f2bf(v1.y); o[6] = f2bf(v1.z); o[7] = f2bf(v1.w);
        *(us8*)&w1_bf[(size_t)id * 8] = o;
    }
    // ---- y = b2 broadcast (4096x10 = 40960 = 256*160) ----
    if (t < 160) { int id = b * 160 + t; y[id] = b2[id % 10]; }

    // ---- E0 tile (64x64) for blocks 0..63 ----
    if (b < 64) {
        const int m0 = (b >> 3) * 64, n0 = (b & 7) * 64;
        const int r = t >> 2, cq = t & 3;
        float vals[16];
#pragma unroll
        for (int u = 0; u < 4; ++u) {
            float4 a = *(const float4*)&Ain[(size_t)(m0 + r) * 512 + n0 + cq * 16 + u * 4];
            vals[u * 4 + 0] = dt * a.x; vals[u * 4 + 1] = dt * a.y;
            vals[u * 4 + 2] = dt * a.z; vals[u * 4 + 3] = dt * a.w;
        }
#pragma unroll
        for (int u = 0; u < 4; ++u)
            *(float4*)&E[(size_t)(m0 + r) * 512 + n0 + cq * 16 + u * 4] =
                make_float4(vals[u * 4], vals[u * 4 + 1], vals[u * 4 + 2], vals[u * 4 + 3]);
        us8 h0, h1;
#pragma unroll
        for (int j = 0; j < 8; ++j) { h0[j] = f2bf(vals[j]); h1[j] = f2bf(vals[8 + j]); }
        *(us8*)&hi[(size_t)(m0 + r) * 512 + n0 + cq * 16]     = h0;
        *(us8*)&hi[(size_t)(m0 + r) * 512 + n0 + cq * 16 + 8] = h1;
#pragma unroll
        for (int j = 0; j < 16; ++j) epi[r * 68 + cq * 16 + j] = vals[j];
        __syncthreads();
        const int cf = t >> 2, rq = t & 3;
        us8 o0, o1;
#pragma unroll
        for (int i = 0; i < 8; ++i) {
            o0[i] = f2bf(epi[(rq * 16 + i) * 68 + cf]);
            o1[i] = f2bf(epi[(rq * 16 + 8 + i) * 68 + cf]);
        }
        *(us8*)&hiT[(size_t)(n0 + cf) * 512 + m0 + rq * 16]     = o0;
        *(us8*)&hiT[(size_t)(n0 + cf) * 512 + m0 + rq * 16 + 8] = o1;
    }
}

// ===========================================================================
// k_sq (grid 64 x 256): E' = 2E + E*E via bf16 MFMA (E-form squaring).
// A-side = hi rows, B-side = hiT rows (MFMA computes A*B^T). Emits fp32 E',
// bf16 hi', transposed bf16 hiT' (LDS bounce).
// ===========================================================================
union SqSmem {
    struct { unsigned short A[64 * 64]; unsigned short B[64 * 64]; } s; // 16 KB
    float epi[64 * 68];                                                 // 17.4 KB
};

__device__ inline void gemm64_mfma(const unsigned short* __restrict__ Arows,
                                   const unsigned short* __restrict__ Brows,
                                   int m0, int n0, int t, SqSmem& sm,
                                   f32x4 acc[2][2]) {
    const int lane = t & 63, w = t >> 6, quad = lane >> 4, l16 = lane & 15;
    const int wm = (w & 1) * 32, wn = (w >> 1) * 32;
#pragma unroll
    for (int i = 0; i < 2; ++i)
#pragma unroll
        for (int j = 0; j < 2; ++j) acc[i][j] = (f32x4){0.f, 0.f, 0.f, 0.f};
    for (int kt = 0; kt < 8; ++kt) {
#pragma unroll
        for (int c = 0; c < 2; ++c) {
            int idx = c * 256 + t, row = idx >> 3, cc = idx & 7;
            int ccs = cc ^ (row & 7);
            *(us8*)&sm.s.A[row * 64 + ccs * 8] =
                *(const us8*)&Arows[(size_t)(m0 + row) * 512 + kt * 64 + cc * 8];
            *(us8*)&sm.s.B[row * 64 + ccs * 8] =
                *(const us8*)&Brows[(size_t)(n0 + row) * 512 + kt * 64 + cc * 8];
        }
        __syncthreads();
#pragma unroll
        for (int ks = 0; ks < 2; ++ks) {
            bf16x8 af[2], bfr[2];
#pragma unroll
            for (int i = 0; i < 2; ++i) {
                int ra = wm + i * 16 + l16, ca = (ks * 4 + quad) ^ (ra & 7);
                af[i] = *(const bf16x8*)&sm.s.A[ra * 64 + ca * 8];
                int rb = wn + i * 16 + l16, cb = (ks * 4 + quad) ^ (rb & 7);
                bfr[i] = *(const bf16x8*)&sm.s.B[rb * 64 + cb * 8];
            }
#pragma unroll
            for (int i = 0; i < 2; ++i)
#pragma unroll
                for (int j = 0; j < 2; ++j)
                    acc[i][j] = __builtin_amdgcn_mfma_f32_16x16x32_bf16(
                        af[i], bfr[j], acc[i][j], 0, 0, 0);
        }
        __syncthreads();
    }
    // dump accumulators to epi[r*68+c]
#pragma unroll
    for (int i = 0; i < 2; ++i)
#pragma unroll
        for (int j = 0; j < 2; ++j)
#pragma unroll
            for (int rr = 0; rr < 4; ++rr)
                sm.epi[(wm + i * 16 + quad * 4 + rr) * 68 + wn + j * 16 + l16] =
                    acc[i][j][rr];
    __syncthreads();
}

__global__ __launch_bounds__(256) void k_sq(
    const float* __restrict__ E, const unsigned short* __restrict__ hi,
    const unsigned short* __restrict__ hiT, float* __restrict__ Eo,
    unsigned short* __restrict__ hio, unsigned short* __restrict__ hiTo) {
    __shared__ SqSmem sm;
    const int t = threadIdx.x, b = blockIdx.x;
    const int m0 = (b >> 3) * 64, n0 = (b & 7) * 64;
    f32x4 acc[2][2];
    gemm64_mfma(hi, hiT, m0, n0, t, sm, acc);
    // epilogue: E' = 2E + P
    {
        const int r = t >> 2, cq = t & 3;
        float e2[16];
#pragma unroll
        for (int u = 0; u < 4; ++u) {
            float4 ev = *(const float4*)&E[(size_t)(m0 + r) * 512 + n0 + cq * 16 + u * 4];
            e2[u * 4 + 0] = 2.f * ev.x + sm.epi[r * 68 + cq * 16 + u * 4 + 0];
            e2[u * 4 + 1] = 2.f * ev.y + sm.epi[r * 68 + cq * 16 + u * 4 + 1];
            e2[u * 4 + 2] = 2.f * ev.z + sm.epi[r * 68 + cq * 16 + u * 4 + 2];
            e2[u * 4 + 3] = 2.f * ev.w + sm.epi[r * 68 + cq * 16 + u * 4 + 3];
        }
#pragma unroll
        for (int u = 0; u < 4; ++u)
            *(float4*)&Eo[(size_t)(m0 + r) * 512 + n0 + cq * 16 + u * 4] =
                make_float4(e2[u * 4], e2[u * 4 + 1], e2[u * 4 + 2], e2[u * 4 + 3]);
        us8 h0, h1;
#pragma unroll
        for (int j = 0; j < 8; ++j) { h0[j] = f2bf(e2[j]); h1[j] = f2bf(e2[8 + j]); }
        *(us8*)&hio[(size_t)(m0 + r) * 512 + n0 + cq * 16]     = h0;
        *(us8*)&hio[(size_t)(m0 + r) * 512 + n0 + cq * 16 + 8] = h1;
#pragma unroll
        for (int j = 0; j < 16; ++j) sm.epi[r * 68 + cq * 16 + j] = e2[j];
    }
    __syncthreads();
    {
        const int cf = t >> 2, rq = t & 3;
        us8 o0, o1;
#pragma unroll
        for (int i = 0; i < 8; ++i) {
            o0[i] = f2bf(sm.epi[(rq * 16 + i) * 68 + cf]);
            o1[i] = f2bf(sm.epi[(rq * 16 + 8 + i) * 68 + cf]);
        }
        *(us8*)&hiTo[(size_t)(n0 + cf) * 512 + m0 + rq * 16]     = o0;
        *(us8*)&hiTo[(size_t)(n0 + cf) * 512 + m0 + rq * 16 + 8] = o1;
    }
}

// ===========================================================================
// k_fold (grid 256 x 256): w1f = bf16(W1 + W1_bf * E6)  (A*B^T, B = hiT)
// ===========================================================================
__global__ __launch_bounds__(256) void k_fold(
    const unsigned short* __restrict__ w1_bf,
    const unsigned short* __restrict__ hiT, const float* __restrict__ W1,
    unsigned short* __restrict__ w1f) {
    __shared__ SqSmem sm;
    const int t = threadIdx.x, b = blockIdx.x;
    const int m0 = (b >> 3) * 64, n0 = (b & 7) * 64;
    f32x4 acc[2][2];
    gemm64_mfma(w1_bf, hiT, m0, n0, t, sm, acc);
    const int r = t >> 2, cq = t & 3;
    float e2[16];
#pragma unroll
    for (int u = 0; u < 4; ++u) {
        float4 wv = *(const float4*)&W1[(size_t)(m0 + r) * 512 + n0 + cq * 16 + u * 4];
        e2[u * 4 + 0] = wv.x + sm.epi[r * 68 + cq * 16 + u * 4 + 0];
        e2[u * 4 + 1] = wv.y + sm.epi[r * 68 + cq * 16 + u * 4 + 1];
        e2[u * 4 + 2] = wv.z + sm.epi[r * 68 + cq * 16 + u * 4 + 2];
        e2[u * 4 + 3] = wv.w + sm.epi[r * 68 + cq * 16 + u * 4 + 3];
    }
    us8 h0, h1;
#pragma unroll
    for (int j = 0; j < 8; ++j) { h0[j] = f2bf(e2[j]); h1[j] = f2bf(e2[8 + j]); }
    *(us8*)&w1f[(size_t)(m0 + r) * 512 + n0 + cq * 16]     = h0;
    *(us8*)&w1f[(size_t)(m0 + r) * 512 + n0 + cq * 16 + 8] = h1;
}

// ===========================================================================
// Main GEMM (unchanged from round 2, PASSING): h = relu(x_bf @ w1f^T + b1)
// fused with y += h @ W2^T (atomicAdd).
// ===========================================================================
union SmemU {
    struct { unsigned short A[128 * 64]; unsigned short B[128 * 64]; } s; // 32 KB
    struct { unsigned short h[128 * 130]; float w2[DY * 132]; } e;        // 38.6 KB
};

__global__ __launch_bounds__(256, 2) void mlp_kernel(
    const unsigned short* __restrict__ x_bf,
    const unsigned short* __restrict__ w1f,
    const float* __restrict__ b1, const float* __restrict__ W2,
    float* __restrict__ y) {
    __shared__ SmemU sm;
    const int t    = threadIdx.x;
    const int lane = t & 63, w = t >> 6;
    const int quad = lane >> 4, l16 = lane & 15;
    const int wm = (w & 1) * 64, wn = (w >> 1) * 64;
    const int m0g = blockIdx.x * 128, n0g = blockIdx.y * 128;

    f32x4 acc[4][4];
#pragma unroll
    for (int i = 0; i < 4; ++i)
#pragma unroll
        for (int j = 0; j < 4; ++j) acc[i][j] = (f32x4){0.f, 0.f, 0.f, 0.f};

    for (int kt = 0; kt < 8; ++kt) {
#pragma unroll
        for (int c = 0; c < 4; ++c) {
            int idx = c * 256 + t;
            int row = idx >> 3, cc = idx & 7;
            int ccs = cc ^ (row & 7);
            us8 va = *(const us8*)&x_bf[(size_t)(m0g + row) * 512 + kt * 64 + cc * 8];
            *(us8*)&sm.s.A[row * 64 + ccs * 8] = va;
            us8 vb = *(const us8*)&w1f[(size_t)(n0g + row) * 512 + kt * 64 + cc * 8];
            *(us8*)&sm.s.B[row * 64 + ccs * 8] = vb;
        }
        __syncthreads();
#pragma unroll
        for (int ks = 0; ks < 2; ++ks) {
            bf16x8 af[4], bfr[4];
#pragma unroll
            for (int i = 0; i < 4; ++i) {
                int ra = wm + i * 16 + l16;
                int rb = wn + i * 16 + l16;
                int ca = (ks * 4 + quad) ^ (ra & 7);
                int cb = (ks * 4 + quad) ^ (rb & 7);
                af[i]  = *(const bf16x8*)&sm.s.A[ra * 64 + ca * 8];
                bfr[i] = *(const bf16x8*)&sm.s.B[rb * 64 + cb * 8];
            }
#pragma unroll
            for (int i = 0; i < 4; ++i)
#pragma unroll
                for (int j = 0; j < 4; ++j)
                    acc[i][j] = __builtin_amdgcn_mfma_f32_16x16x32_bf16(
                        af[i], bfr[j], acc[i][j], 0, 0, 0);
        }
        __syncthreads();
    }

    float bias[4];
#pragma unroll
    for (int j = 0; j < 4; ++j) bias[j] = b1[n0g + wn + j * 16 + l16];
#pragma unroll
    for (int i = 0; i < 4; ++i)
#pragma unroll
        for (int j = 0; j < 4; ++j)
#pragma unroll
            for (int r = 0; r < 4; ++r) {
                float h = acc[i][j][r] + bias[j];
                h = h > 0.f ? h : 0.f;
                sm.e.h[(wn + j * 16 + l16) * 130 + (wm + i * 16 + quad * 4 + r)] = f2bf(h);
            }
    for (int i = t; i < DY * 128; i += 256) {
        int d = i >> 7, n = i & 127;
        sm.e.w2[d * 132 + n] = W2[(size_t)d * H_SZ + n0g + n];
    }
    __syncthreads();
    {
        int m = t >> 1, dg = t & 1;
        float s0 = 0.f, s1 = 0.f, s2 = 0.f, s3 = 0.f, s4 = 0.f;
        const float* wrow = &sm.e.w2[dg * 5 * 132];
#pragma unroll 4
        for (int n = 0; n < 128; ++n) {
            float h = bf2f(sm.e.h[n * 130 + m]);
            s0 += h * wrow[n];
            s1 += h * wrow[132 + n];
            s2 += h * wrow[264 + n];
            s3 += h * wrow[396 + n];
            s4 += h * wrow[528 + n];
        }
        float* yp = &y[(size_t)(m0g + m) * DY + dg * 5];
        atomicAdd(yp + 0, s0);
        atomicAdd(yp + 1, s1);
        atomicAdd(yp + 2, s2);
        atomicAdd(yp + 3, s3);
        atomicAdd(yp + 4, s4);
    }
}

// ===========================================================================
extern "C" void kernel_launch(void* const* d_in, const int* in_sizes, int n_in,
                              void* d_out, int out_size, void* d_ws, size_t ws_size,
                              hipStream_t stream) {
    const float* x  = (const float*)d_in[0];
    const float* A  = (const float*)d_in[1];
    const float* W1 = (const float*)d_in[2];
    const float* b1 = (const float*)d_in[3];
    const float* W2 = (const float*)d_in[4];
    const float* b2 = (const float*)d_in[5];
    float* y = (float*)d_out;

    char* ws = (char*)d_ws;
    const size_t MB = 1u << 20;
    float* Ea = (float*)ws;
    float* Eb = (float*)(ws + 1 * MB);
    unsigned short* hiA  = (unsigned short*)(ws + 2 * MB);
    unsigned short* hiTA = (unsigned short*)(ws + 2 * MB + 512 * 1024);
    unsigned short* hiB  = (unsigned short*)(ws + 3 * MB);
    unsigned short* hiTB = (unsigned short*)(ws + 3 * MB + 512 * 1024);
    unsigned short* x_bf  = (unsigned short*)(ws + 4 * MB);  // 4 MB
    unsigned short* w1_bf = (unsigned short*)(ws + 8 * MB);  // 2 MB
    unsigned short* w1f   = (unsigned short*)(ws + 10 * MB); // 2 MB

    k_init<<<256, 256, 0, stream>>>(A, x, W1, b2, Ea, hiA, hiTA, x_bf, w1_bf, y);
    k_sq<<<64, 256, 0, stream>>>(Ea, hiA, hiTA, Eb, hiB, hiTB);
    k_sq<<<64, 256, 0, stream>>>(Eb, hiB, hiTB, Ea, hiA, hiTA);
    k_sq<<<64, 256, 0, stream>>>(Ea, hiA, hiTA, Eb, hiB, hiTB);
    k_sq<<<64, 256, 0, stream>>>(Eb, hiB, hiTB, Ea, hiA, hiTA);
    k_sq<<<64, 256, 0, stream>>>(Ea, hiA, hiTA, Eb, hiB, hiTB);
    k_sq<<<64, 256, 0, stream>>>(Eb, hiB, hiTB, Ea, hiA, hiTA);
    k_fold<<<256, 256, 0, stream>>>(w1_bf, hiTA, W1, w1f);
    mlp_kernel<<<dim3(32, 16), dim3(256), 0, stream>>>(x_bf, w1f, b1, W2, y);
}